// Round 1
// baseline (1101.365 us; speedup 1.0000x reference)
//
#include <hip/hip_runtime.h>
#include <math.h>

#define BB 32
#define LL 2048
#define EE 512
#define HH 512
#define RT 16

__device__ __forceinline__ void online_update(float& m, float& s, float& o,
                                              float x, float ev) {
  float mn = fmaxf(m, x);
  float sc = __expf(m - mn);   // m=-1e30 -> underflows to 0, no NaN
  float p  = __expf(x - mn);
  s = s * sc + p;
  o = o * sc + p * ev;
  m = mn;
}

__global__ __launch_bounds__(256) void attn_partial(
    const float* __restrict__ enc, const int* __restrict__ lens,
    const float* __restrict__ Wh, const float* __restrict__ bh,
    const float* __restrict__ Wc,
    float* __restrict__ pm, float* __restrict__ ps, float* __restrict__ po,
    int C, int Lc)
{
  const int c   = blockIdx.x;
  const int b   = blockIdx.y;
  const int tid = threadIdx.x;
  const int e0  = tid;
  const int e1  = tid + 256;

  const int n      = lens[b];
  const int l0     = c * Lc;
  const int nvalid = min(n - l0, Lc);   // may be <= 0 (chunk fully padded)

  float m0 = -1e30f, s0 = 0.f, o0 = 0.f;
  float m1 = -1e30f, s1 = 0.f, o1 = 0.f;

  __shared__ float encT[RT][EE];  // 32 KiB
  __shared__ float hT[RT][HH];    // 32 KiB

  const float bh0 = bh[e0];
  const float bh1 = bh[e1];

  for (int r0 = 0; r0 < nvalid; r0 += RT) {
    const int rows = min(RT, nvalid - r0);

    // ---- stage enc tile (always full RT rows; in-bounds since Lc % RT == 0) ----
    for (int idx = tid; idx < RT * EE; idx += 256) {
      const int r = idx >> 9;
      const int e = idx & 511;
      encT[r][e] = enc[((size_t)b * LL + (l0 + r0 + r)) * EE + e];
    }
    __syncthreads();

    // ---- phase 2: h = tanh(enc @ Wh + bh), thread owns cols e0,e1 ----
    {
      float acc[RT][2];
#pragma unroll
      for (int r = 0; r < RT; r++) { acc[r][0] = bh0; acc[r][1] = bh1; }

      for (int e = 0; e < EE; e += 4) {
        const float w00 = Wh[(size_t)(e + 0) * HH + e0];
        const float w01 = Wh[(size_t)(e + 1) * HH + e0];
        const float w02 = Wh[(size_t)(e + 2) * HH + e0];
        const float w03 = Wh[(size_t)(e + 3) * HH + e0];
        const float w10 = Wh[(size_t)(e + 0) * HH + e1];
        const float w11 = Wh[(size_t)(e + 1) * HH + e1];
        const float w12 = Wh[(size_t)(e + 2) * HH + e1];
        const float w13 = Wh[(size_t)(e + 3) * HH + e1];
#pragma unroll
        for (int r = 0; r < RT; r++) {
          const float4 ev = *(const float4*)&encT[r][e];
          acc[r][0] = fmaf(ev.x, w00, acc[r][0]);
          acc[r][0] = fmaf(ev.y, w01, acc[r][0]);
          acc[r][0] = fmaf(ev.z, w02, acc[r][0]);
          acc[r][0] = fmaf(ev.w, w03, acc[r][0]);
          acc[r][1] = fmaf(ev.x, w10, acc[r][1]);
          acc[r][1] = fmaf(ev.y, w11, acc[r][1]);
          acc[r][1] = fmaf(ev.z, w12, acc[r][1]);
          acc[r][1] = fmaf(ev.w, w13, acc[r][1]);
        }
      }
#pragma unroll
      for (int r = 0; r < RT; r++) {
        hT[r][e0] = tanhf(acc[r][0]);
        hT[r][e1] = tanhf(acc[r][1]);
      }
    }
    __syncthreads();

    // ---- phase 3: logits = h @ Wc, consumed immediately into online softmax ----
    {
      float acc[RT][2];
#pragma unroll
      for (int r = 0; r < RT; r++) { acc[r][0] = 0.f; acc[r][1] = 0.f; }

      for (int h = 0; h < HH; h += 4) {
        const float w00 = Wc[(size_t)(h + 0) * EE + e0];
        const float w01 = Wc[(size_t)(h + 1) * EE + e0];
        const float w02 = Wc[(size_t)(h + 2) * EE + e0];
        const float w03 = Wc[(size_t)(h + 3) * EE + e0];
        const float w10 = Wc[(size_t)(h + 0) * EE + e1];
        const float w11 = Wc[(size_t)(h + 1) * EE + e1];
        const float w12 = Wc[(size_t)(h + 2) * EE + e1];
        const float w13 = Wc[(size_t)(h + 3) * EE + e1];
#pragma unroll
        for (int r = 0; r < RT; r++) {
          const float4 hv = *(const float4*)&hT[r][h];
          acc[r][0] = fmaf(hv.x, w00, acc[r][0]);
          acc[r][0] = fmaf(hv.y, w01, acc[r][0]);
          acc[r][0] = fmaf(hv.z, w02, acc[r][0]);
          acc[r][0] = fmaf(hv.w, w03, acc[r][0]);
          acc[r][1] = fmaf(hv.x, w10, acc[r][1]);
          acc[r][1] = fmaf(hv.y, w11, acc[r][1]);
          acc[r][1] = fmaf(hv.z, w12, acc[r][1]);
          acc[r][1] = fmaf(hv.w, w13, acc[r][1]);
        }
      }
      // ---- phase 4: masked online-softmax update ----
#pragma unroll
      for (int r = 0; r < RT; r++) {
        if (r < rows) {
          online_update(m0, s0, o0, acc[r][0], encT[r][e0]);
          online_update(m1, s1, o1, acc[r][1], encT[r][e1]);
        }
      }
    }
    __syncthreads();   // protect encT/hT before next staging
  }

  const size_t base = ((size_t)b * C + c) * EE;
  pm[base + e0] = m0; pm[base + e1] = m1;
  ps[base + e0] = s0; ps[base + e1] = s1;
  po[base + e0] = o0; po[base + e1] = o1;
}

__global__ __launch_bounds__(256) void attn_combine(
    const float* __restrict__ pm, const float* __restrict__ ps,
    const float* __restrict__ po, float* __restrict__ out, int C)
{
  const int b   = blockIdx.x;
  const int tid = threadIdx.x;
#pragma unroll
  for (int half = 0; half < 2; half++) {
    const int e = tid + half * 256;
    float M = -1e30f, S = 0.f, O = 0.f;
    for (int c = 0; c < C; c++) {
      const size_t base = ((size_t)b * C + c) * EE;
      const float m = pm[base + e];
      const float s = ps[base + e];
      const float o = po[base + e];
      const float Mn  = fmaxf(M, m);
      const float sc0 = __expf(M - Mn);
      const float sc1 = __expf(m - Mn);
      S = S * sc0 + s * sc1;
      O = O * sc0 + o * sc1;
      M = Mn;
    }
    out[(size_t)b * EE + e] = O / S;   // S > 0 since lengths >= 1
  }
}

extern "C" void kernel_launch(void* const* d_in, const int* in_sizes, int n_in,
                              void* d_out, int out_size, void* d_ws, size_t ws_size,
                              hipStream_t stream) {
  const float* enc  = (const float*)d_in[0];
  const int*   lens = (const int*)d_in[1];
  const float* Wh   = (const float*)d_in[2];
  const float* bh   = (const float*)d_in[3];
  const float* Wc   = (const float*)d_in[4];
  float* out = (float*)d_out;

  int C = 16;  // 512 blocks = 2 per CU
  if (ws_size < (size_t)3 * BB * C * EE * sizeof(float)) C = 1;  // safety fallback
  const int Lc = LL / C;

  float* pm = (float*)d_ws;
  float* ps = pm + (size_t)BB * C * EE;
  float* po = ps + (size_t)BB * C * EE;

  dim3 grid(C, BB);
  attn_partial<<<grid, 256, 0, stream>>>(enc, lens, Wh, bh, Wc, pm, ps, po, C, Lc);
  attn_combine<<<BB, 256, 0, stream>>>(pm, ps, po, out, C);
}

// Round 2
// 446.116 us; speedup vs baseline: 2.4688x; 2.4688x over previous
//
#include <hip/hip_runtime.h>
#include <math.h>

#define BB 32
#define LL 2048
#define EE 512
#define HH 512

typedef __bf16 bf16_t;
typedef bf16_t bf16x8 __attribute__((ext_vector_type(8)));
typedef float f32x4 __attribute__((ext_vector_type(4)));
typedef unsigned short u16x8 __attribute__((ext_vector_type(8)));

__device__ __forceinline__ unsigned short f2bf(float f) {
  unsigned int u = __builtin_bit_cast(unsigned int, f);
  unsigned int r = (u + 0x7FFFu + ((u >> 16) & 1u)) >> 16;  // RNE
  return (unsigned short)r;
}
__device__ __forceinline__ float bf2f(unsigned short s) {
  unsigned int u = ((unsigned int)s) << 16;
  return __builtin_bit_cast(float, u);
}
__device__ __forceinline__ bf16x8 ld_frag_lds(const unsigned short* p) {
  u16x8 raw = *(const u16x8*)p;
  return __builtin_bit_cast(bf16x8, raw);
}
__device__ __forceinline__ bf16x8 ld_frag_g(const unsigned short* p) {
  u16x8 raw = *(const u16x8*)p;
  return __builtin_bit_cast(bf16x8, raw);
}
__device__ __forceinline__ float tanh_fast(float x) {
  x = fminf(fmaxf(x, -15.f), 15.f);
  float e2 = __expf(2.f * x);
  return (e2 - 1.f) / (e2 + 1.f);
}

// ---------------- prep: transpose + fp32->bf16 convert of Wh, Wc ----------------
// WhT[h][e] = Wh[e][h];  WcT[e][h] = Wc[h][e]   (both 512x512)
__global__ __launch_bounds__(256) void prep_w(
    const float* __restrict__ Wh, const float* __restrict__ Wc,
    unsigned short* __restrict__ WhT, unsigned short* __restrict__ WcT)
{
  const float* src = blockIdx.y ? Wc : Wh;
  unsigned short* dst = blockIdx.y ? WcT : WhT;
  const int tr = (blockIdx.x >> 3) * 64;  // source row base
  const int tc = (blockIdx.x & 7) * 64;   // source col base
  const int tid = threadIdx.x;
  __shared__ float tile[64][65];
  for (int i = tid; i < 64 * 16; i += 256) {
    const int r = i >> 4, c4 = (i & 15) << 2;
    const float4 v = *(const float4*)(src + (size_t)(tr + r) * 512 + tc + c4);
    tile[r][c4 + 0] = v.x; tile[r][c4 + 1] = v.y;
    tile[r][c4 + 2] = v.z; tile[r][c4 + 3] = v.w;
  }
  __syncthreads();
  for (int i = tid; i < 64 * 16; i += 256) {
    const int r = i >> 4, c4 = (i & 15) << 2;
    ushort4 pk;
    pk.x = f2bf(tile[c4 + 0][r]); pk.y = f2bf(tile[c4 + 1][r]);
    pk.z = f2bf(tile[c4 + 2][r]); pk.w = f2bf(tile[c4 + 3][r]);
    *(ushort4*)(dst + (size_t)(tc + r) * 512 + tr + c4) = pk;
  }
}

// ---------------- main: per-(b,chunk) fused GEMM1+tanh+GEMM2+online-softmax ----------------
__global__ __launch_bounds__(256, 2) void attn_main(
    const float* __restrict__ enc, const int* __restrict__ lens,
    const unsigned short* __restrict__ WhT, const float* __restrict__ bh,
    const unsigned short* __restrict__ WcT,
    float* __restrict__ pm, float* __restrict__ ps, float* __restrict__ po,
    int C, int Lc)
{
  const int c = blockIdx.x;
  const int b = blockIdx.y;
  const int n = lens[b];
  const int l0 = c * Lc;
  const int nvalid = min(n - l0, Lc);
  if (nvalid <= 0) return;

  const int tid  = threadIdx.x;
  const int wave = tid >> 6;
  const int lane = tid & 63;
  const int quad = lane >> 4;
  const int l15  = lane & 15;
  const int wbase = wave * 128;  // wave's h-range (GEMM1) and e-range (GEMM2)

  __shared__ __align__(16) unsigned short encA[32 * 520];  // enc tile bf16 [m][e], padded stride
  __shared__ __align__(16) unsigned short hS[32 * 520];    // h tile bf16 [m][h], padded stride
  __shared__ __align__(16) float bhS[512];

  // per-thread online state for its 8 feature columns e = wbase + et*16 + l15
  float stM[8], stS[8], stO[8];
#pragma unroll
  for (int et = 0; et < 8; et++) { stM[et] = -1e30f; stS[et] = 0.f; stO[et] = 0.f; }

  bhS[tid] = bh[tid];
  bhS[tid + 256] = bh[tid + 256];

  for (int r0 = 0; r0 < nvalid; r0 += 32) {
    // ---- stage enc tile -> bf16 LDS (rows beyond nvalid hold finite garbage; masked later) ----
    const float* encRow = enc + ((size_t)b * LL + l0 + r0) * EE;
    for (int i = tid; i < 32 * 128; i += 256) {
      const int m = i >> 7, e4 = (i & 127) << 2;
      const float4 v = *(const float4*)(encRow + (size_t)m * EE + e4);
      ushort4 pk;
      pk.x = f2bf(v.x); pk.y = f2bf(v.y); pk.z = f2bf(v.z); pk.w = f2bf(v.w);
      *(ushort4*)&encA[m * 520 + e4] = pk;
    }
    __syncthreads();

    // ---- GEMM1': hT[H x 32] = WhT (A, global) @ encT (B, LDS) ----
    f32x4 acc1[8][2];
#pragma unroll
    for (int ht = 0; ht < 8; ht++)
      for (int mt = 0; mt < 2; mt++) acc1[ht][mt] = (f32x4){0.f, 0.f, 0.f, 0.f};

#pragma unroll 2
    for (int k0 = 0; k0 < 512; k0 += 32) {
      bf16x8 bfr[2];
#pragma unroll
      for (int mt = 0; mt < 2; mt++)
        bfr[mt] = ld_frag_lds(&encA[(mt * 16 + l15) * 520 + k0 + quad * 8]);
      bf16x8 af[8];
#pragma unroll
      for (int ht = 0; ht < 8; ht++)
        af[ht] = ld_frag_g(WhT + ((size_t)(wbase + ht * 16 + l15) * 512 + k0 + quad * 8));
#pragma unroll
      for (int ht = 0; ht < 8; ht++) {
        acc1[ht][0] = __builtin_amdgcn_mfma_f32_16x16x32_bf16(af[ht], bfr[0], acc1[ht][0], 0, 0, 0);
        acc1[ht][1] = __builtin_amdgcn_mfma_f32_16x16x32_bf16(af[ht], bfr[1], acc1[ht][1], 0, 0, 0);
      }
    }

    // ---- bias + tanh, pack 4 consecutive h -> one 8B LDS write of h[m][h] ----
#pragma unroll
    for (int ht = 0; ht < 8; ht++) {
      const f32x4 bv = *(const f32x4*)&bhS[wbase + ht * 16 + quad * 4];
#pragma unroll
      for (int mt = 0; mt < 2; mt++) {
        ushort4 pk;
        pk.x = f2bf(tanh_fast(acc1[ht][mt][0] + bv[0]));
        pk.y = f2bf(tanh_fast(acc1[ht][mt][1] + bv[1]));
        pk.z = f2bf(tanh_fast(acc1[ht][mt][2] + bv[2]));
        pk.w = f2bf(tanh_fast(acc1[ht][mt][3] + bv[3]));
        *(ushort4*)&hS[(mt * 16 + l15) * 520 + wbase + ht * 16 + quad * 4] = pk;
      }
    }
    __syncthreads();

    // ---- GEMM2: logits[32 x E] = h (A, LDS) @ Wc (B = WcT, global) ----
    f32x4 acc2[2][8];
#pragma unroll
    for (int mt = 0; mt < 2; mt++)
      for (int et = 0; et < 8; et++) acc2[mt][et] = (f32x4){0.f, 0.f, 0.f, 0.f};

#pragma unroll 2
    for (int k0 = 0; k0 < 512; k0 += 32) {
      bf16x8 afr[2];
#pragma unroll
      for (int mt = 0; mt < 2; mt++)
        afr[mt] = ld_frag_lds(&hS[(mt * 16 + l15) * 520 + k0 + quad * 8]);
      bf16x8 bfw[8];
#pragma unroll
      for (int et = 0; et < 8; et++)
        bfw[et] = ld_frag_g(WcT + ((size_t)(wbase + et * 16 + l15) * 512 + k0 + quad * 8));
#pragma unroll
      for (int et = 0; et < 8; et++) {
        acc2[0][et] = __builtin_amdgcn_mfma_f32_16x16x32_bf16(afr[0], bfw[et], acc2[0][et], 0, 0, 0);
        acc2[1][et] = __builtin_amdgcn_mfma_f32_16x16x32_bf16(afr[1], bfw[et], acc2[1][et], 0, 0, 0);
      }
    }

    // ---- phase 4: masked online softmax over the 32 time rows of this pass ----
    bool ok[2][4];
#pragma unroll
    for (int mt = 0; mt < 2; mt++)
#pragma unroll
      for (int r = 0; r < 4; r++)
        ok[mt][r] = (r0 + mt * 16 + quad * 4 + r) < nvalid;

#pragma unroll
    for (int et = 0; et < 8; et++) {
      const int e = wbase + et * 16 + l15;
      float v[2][4];
      float lm = -1e30f;
#pragma unroll
      for (int mt = 0; mt < 2; mt++)
#pragma unroll
        for (int r = 0; r < 4; r++) {
          v[mt][r] = ok[mt][r] ? acc2[mt][et][r] : -1e30f;
          lm = fmaxf(lm, v[mt][r]);
        }
      lm = fmaxf(lm, __shfl_xor(lm, 16));
      lm = fmaxf(lm, __shfl_xor(lm, 32));
      float ls = 0.f, lo = 0.f;
#pragma unroll
      for (int mt = 0; mt < 2; mt++)
#pragma unroll
        for (int r = 0; r < 4; r++) {
          const float p  = __expf(v[mt][r] - lm);  // 0 for masked rows
          const float ev = bf2f(encA[(mt * 16 + quad * 4 + r) * 520 + e]);
          ls += p;
          lo += p * ev;
        }
      ls += __shfl_xor(ls, 16); ls += __shfl_xor(ls, 32);
      lo += __shfl_xor(lo, 16); lo += __shfl_xor(lo, 32);
      // merge tile partial into running state
      const float Mn = fmaxf(stM[et], lm);
      const float sc = __expf(stM[et] - Mn);
      const float st = __expf(lm - Mn);
      stS[et] = stS[et] * sc + ls * st;
      stO[et] = stO[et] * sc + lo * st;
      stM[et] = Mn;
    }
    __syncthreads();  // protect encA/hS before next pass staging
  }

  // ---- write per-chunk partials (one writer lane per 16-lane group) ----
  if (quad == 0) {
    const size_t base = ((size_t)b * C + c) * EE;
#pragma unroll
    for (int et = 0; et < 8; et++) {
      const int e = wbase + et * 16 + l15;
      pm[base + e] = stM[et];
      ps[base + e] = stS[et];
      po[base + e] = stO[et];
    }
  }
}

// ---------------- combine over chunks ----------------
__global__ __launch_bounds__(256) void attn_combine(
    const float* __restrict__ pm, const float* __restrict__ ps,
    const float* __restrict__ po, const int* __restrict__ lens,
    float* __restrict__ out, int C, int Lc)
{
  const int b = blockIdx.x;
  const int tid = threadIdx.x;
  const int n = lens[b];
  const int cmax = min(C, (n + Lc - 1) / Lc);
#pragma unroll
  for (int half = 0; half < 2; half++) {
    const int e = tid + half * 256;
    float M = -1e30f, S = 0.f, O = 0.f;
    for (int c = 0; c < cmax; c++) {
      const size_t base = ((size_t)b * C + c) * EE;
      const float m = pm[base + e];
      const float s = ps[base + e];
      const float o = po[base + e];
      const float Mn  = fmaxf(M, m);
      const float sc0 = __expf(M - Mn);
      const float sc1 = __expf(m - Mn);
      S = S * sc0 + s * sc1;
      O = O * sc0 + o * sc1;
      M = Mn;
    }
    out[(size_t)b * EE + e] = O / S;
  }
}

extern "C" void kernel_launch(void* const* d_in, const int* in_sizes, int n_in,
                              void* d_out, int out_size, void* d_ws, size_t ws_size,
                              hipStream_t stream) {
  const float* enc  = (const float*)d_in[0];
  const int*   lens = (const int*)d_in[1];
  const float* Wh   = (const float*)d_in[2];
  const float* bh   = (const float*)d_in[3];
  const float* Wc   = (const float*)d_in[4];
  float* out = (float*)d_out;

  const size_t wbytes = (size_t)512 * 512 * sizeof(unsigned short);  // per transposed W
  int C = 32;
  {
    size_t need = (size_t)3 * BB * C * EE * sizeof(float) + 2 * wbytes;
    if (ws_size < need) C = 16;
    need = (size_t)3 * BB * C * EE * sizeof(float) + 2 * wbytes;
    if (ws_size < need) C = 8;
  }
  const int Lc = LL / C;

  float* pm = (float*)d_ws;
  float* ps = pm + (size_t)BB * C * EE;
  float* po = ps + (size_t)BB * C * EE;
  unsigned short* WhT = (unsigned short*)(po + (size_t)BB * C * EE);
  unsigned short* WcT = WhT + (size_t)512 * 512;

  prep_w<<<dim3(64, 2), 256, 0, stream>>>(Wh, Wc, WhT, WcT);
  attn_main<<<dim3(C, BB), 256, 0, stream>>>(enc, lens, WhT, bh, WcT, pm, ps, po, C, Lc);
  attn_combine<<<BB, 256, 0, stream>>>(pm, ps, po, lens, out, C, Lc);
}